// Round 4
// baseline (1380.315 us; speedup 1.0000x reference)
//
#include <hip/hip_runtime.h>
#include <hip/hip_bf16.h>
#include <stdint.h>

// ---------------------------------------------------------------------------
// ScRegNet GCN pretrainer fused pipeline, MI355X / gfx950.  Round 4.
// h0 = relu(adj@(x@W0)+b0); h1 = relu(adj@(h0@W1)+b1); emb = adj@(h1@W2)+b2
// logits = gelu(concat(emb[tf],emb[gene])@Wh1+bh1)@Wh2+bh2
//
// R3 -> R4: new 8-phase-style deep-pipelined GEMM (gemm8p) for the three
// adj GEMMs (G2/G4/G6): BM=256 BN=128 BK=64, 512 thr (8 waves 4Mx2N),
// 3-stage LDS ring (144 KiB), counted s_waitcnt vmcnt(6) at tile boundaries
// (loads stay in flight across barriers), setprio around MFMA clusters,
// proven XOR bank-swizzle.  G1/G3/G5/cvt/head unchanged from R3.
// ---------------------------------------------------------------------------

using f32x4  = __attribute__((ext_vector_type(4))) float;
using bf16x8 = __attribute__((ext_vector_type(8))) __bf16;
using u16x8  = __attribute__((ext_vector_type(8))) unsigned short;
using u16x4  = __attribute__((ext_vector_type(4))) unsigned short;

static __device__ __forceinline__ unsigned short f2bf(float f) {
  unsigned u = __builtin_bit_cast(unsigned, f);
  u += 0x7FFFu + ((u >> 16) & 1u);           // RNE (finite inputs only)
  return (unsigned short)(u >> 16);
}
static __device__ __forceinline__ float bf2f(unsigned short h) {
  unsigned u = ((unsigned)h) << 16;
  return __builtin_bit_cast(float, u);
}
// async global->LDS, 16 B per lane. LDS dest: wave-uniform base + lane*16.
static __device__ __forceinline__ void gload_lds16(const void* g, void* l) {
  __builtin_amdgcn_global_load_lds((__attribute__((address_space(1))) void*)(void*)g,
                                   (__attribute__((address_space(3))) void*)l,
                                   16, 0, 0);
}

// --------------------------- small converters ------------------------------

// out[nf][k] = bf16(in[k][nf])   (weights: [K][Nf] fp32 -> [Nf][K] bf16)
__global__ void tcvt_kernel(const float* __restrict__ in,
                            unsigned short* __restrict__ outp, int K, int Nf) {
  int id = blockIdx.x * 256 + threadIdx.x;
  if (id >= K * Nf) return;
  int k = id % K, nf = id / K;
  outp[id] = f2bf(in[(size_t)k * Nf + nf]);
}

// flat fp32 -> bf16 (adj copy), vectorized 8/thread
__global__ void cvt_bf16_kernel(const float* __restrict__ in,
                                unsigned short* __restrict__ outp, size_t n) {
  size_t i = ((size_t)blockIdx.x * blockDim.x + threadIdx.x) * 8;
  size_t stride = (size_t)gridDim.x * blockDim.x * 8;
  for (; i + 8 <= n; i += stride) {
    const float4* p = (const float4*)(in + i);
    float4 a = p[0], b = p[1];
    u16x8 v;
    v[0] = f2bf(a.x); v[1] = f2bf(a.y); v[2] = f2bf(a.z); v[3] = f2bf(a.w);
    v[4] = f2bf(b.x); v[5] = f2bf(b.y); v[6] = f2bf(b.z); v[7] = f2bf(b.w);
    *(u16x8*)(outp + i) = v;
  }
}

// split-K=2 reduce + bias -> bf16   (EMB = P[0] + P[1] + bias)
__global__ void reduce2_kernel(const float* __restrict__ Pp, const float* __restrict__ bias,
                               unsigned short* __restrict__ outp, int MN, int Nf) {
  int i = (blockIdx.x * 256 + threadIdx.x) * 4;
  if (i >= MN) return;
  float4 a = *(const float4*)(Pp + i);
  float4 b = *(const float4*)(Pp + MN + i);
  int col = i & (Nf - 1);
  u16x4 o;
  o[0] = f2bf(a.x + b.x + bias[col + 0]);
  o[1] = f2bf(a.y + b.y + bias[col + 1]);
  o[2] = f2bf(a.z + b.z + bias[col + 2]);
  o[3] = f2bf(a.w + b.w + bias[col + 3]);
  *(u16x4*)(outp + i) = o;
}

// ------------------- deep-pipelined adj GEMM (gemm8p) ----------------------
// C(MxN) = A(MxK) * Bt(NxK)^T, A bf16 [M][K].  BM=256 BN=128 BK=64.
// 512 thr = 8 waves (4M x 2N), per-wave 64x64 out = 4x4 frags 16x16x32.
// LDS: 3-stage ring, per stage A 256x64 (32K) + B 128x64 (16K) -> 144 KiB.
// Pipeline: while computing tile t (ring rb), stage tile t+2 into (rb+2)%3;
// boundary wait = vmcnt(6) (tile t+1's 6 loads are the oldest 6; t+2's 6
// stay in flight) + raw s_barrier.  Per phase (kk=0/1): 8x ds_read_b128
// (XOR-swizzled), 3 stage loads, barrier, lgkmcnt(0)+sched_barrier,
// setprio(1), 16 MFMA, setprio(0), barrier.
// EP: 1 -> bf16 [M][N] relu(acc+bias); 3 -> fp32 [kc][M][N] partial.
template <int EP>
__global__ __launch_bounds__(512, 1)
void gemm8p(const unsigned short* __restrict__ A, const unsigned short* __restrict__ Bt,
            void* __restrict__ Cout, const float* __restrict__ bias,
            int M, int N, int K, int nbx, int Klen) {
  __shared__ __align__(16) unsigned short As[3 * 256 * 64];  // 96 KiB
  __shared__ __align__(16) unsigned short Bs[3 * 128 * 64];  // 48 KiB
  const int t = threadIdx.x, l = t & 63, w = t >> 6;

  int wg = blockIdx.x;
  const int cpx = gridDim.x >> 3;              // gridDim.x % 8 == 0
  wg = (wg & 7) * cpx + (wg >> 3);
  const int mb = wg / nbx, nb = wg % nbx;
  const int kc = blockIdx.y;
  const int koff = kc * Klen;
  const int wr = w >> 1, wc = w & 1;
  const int fr = l & 15, fq = l >> 4;
  const int rxor = (fr & 7) << 3;

  // bias preload BEFORE any staging so vmcnt counting starts clean
  float bv[4];
  if constexpr (EP == 1) {
#pragma unroll
    for (int ni = 0; ni < 4; ++ni)
      bv[ni] = bias[nb * 128 + wc * 64 + ni * 16 + fr];
  }
  asm volatile("s_waitcnt vmcnt(0)" ::: "memory");
  __builtin_amdgcn_sched_barrier(0);

  // staging geometry: 512 thr x 16B; load instr i covers rows i*64..i*64+63
  const int srow = t >> 3;                     // 0..63
  const int sk0  = 8 * ((t & 7) ^ (srow & 7)); // pre-swizzled source k-slot
  const unsigned short* Ag = A  + (size_t)(mb * 256 + srow) * K + koff + sk0;
  const unsigned short* Bg = Bt + (size_t)(nb * 128 + srow) * K + koff + sk0;
  unsigned short* AsL = As + t * 8;
  unsigned short* BsL = Bs + t * 8;

  const int NT = Klen >> 6;

  // prologue: fully stage tiles 0 (buf0) and 1 (buf1)
#pragma unroll
  for (int i = 0; i < 4; ++i)
    gload_lds16(Ag + (size_t)(i * 64) * K, AsL + i * 4096);
#pragma unroll
  for (int i = 0; i < 2; ++i)
    gload_lds16(Bg + (size_t)(i * 64) * K, BsL + i * 4096);
#pragma unroll
  for (int i = 0; i < 4; ++i)
    gload_lds16(Ag + 64 + (size_t)(i * 64) * K, AsL + 16384 + i * 4096);
#pragma unroll
  for (int i = 0; i < 2; ++i)
    gload_lds16(Bg + 64 + (size_t)(i * 64) * K, BsL + 8192 + i * 4096);
  asm volatile("s_waitcnt vmcnt(6)" ::: "memory");  // tile0's 6 drained
  __builtin_amdgcn_sched_barrier(0);
  __builtin_amdgcn_s_barrier();

  f32x4 acc[4][4] = {};
  int rb = 0;
  for (int tt = 0; tt < NT; ++tt) {
    const int s = tt + 2;
    const int sb = (rb >= 1) ? rb - 1 : 2;     // (rb+2)%3
    const unsigned short* Ab = As + rb * 16384;
    const unsigned short* Bb = Bs + rb * 8192;
    const unsigned short* Ags = Ag + (size_t)s * 64;
    const unsigned short* Bgs = Bg + (size_t)s * 64;
    unsigned short* AsS = AsL + sb * 16384;
    unsigned short* BsS = BsL + sb * 8192;

    // ---------------- phase 1: kk = 0 ----------------
    bf16x8 a0[4], b0[4];
#pragma unroll
    for (int mi = 0; mi < 4; ++mi)
      a0[mi] = *(const bf16x8*)&Ab[(wr * 64 + mi * 16 + fr) * 64 + ((fq * 8) ^ rxor)];
#pragma unroll
    for (int ni = 0; ni < 4; ++ni)
      b0[ni] = *(const bf16x8*)&Bb[(wc * 64 + ni * 16 + fr) * 64 + ((fq * 8) ^ rxor)];
    if (s < NT) {
      gload_lds16(Ags, AsS);
      gload_lds16(Ags + (size_t)64 * K, AsS + 4096);
      gload_lds16(Ags + (size_t)128 * K, AsS + 8192);
    }
    __builtin_amdgcn_s_barrier();
    asm volatile("s_waitcnt lgkmcnt(0)" ::: "memory");
    __builtin_amdgcn_sched_barrier(0);
    __builtin_amdgcn_s_setprio(1);
#pragma unroll
    for (int mi = 0; mi < 4; ++mi)
#pragma unroll
      for (int ni = 0; ni < 4; ++ni)
        acc[mi][ni] = __builtin_amdgcn_mfma_f32_16x16x32_bf16(a0[mi], b0[ni],
                                                              acc[mi][ni], 0, 0, 0);
    __builtin_amdgcn_s_setprio(0);
    __builtin_amdgcn_sched_barrier(0);
    __builtin_amdgcn_s_barrier();

    // ---------------- phase 2: kk = 1 ----------------
    bf16x8 a1[4], b1[4];
#pragma unroll
    for (int mi = 0; mi < 4; ++mi)
      a1[mi] = *(const bf16x8*)&Ab[(wr * 64 + mi * 16 + fr) * 64 + ((32 + fq * 8) ^ rxor)];
#pragma unroll
    for (int ni = 0; ni < 4; ++ni)
      b1[ni] = *(const bf16x8*)&Bb[(wc * 64 + ni * 16 + fr) * 64 + ((32 + fq * 8) ^ rxor)];
    if (s < NT) {
      gload_lds16(Ags + (size_t)192 * K, AsS + 12288);
      gload_lds16(Bgs, BsS);
      gload_lds16(Bgs + (size_t)64 * K, BsS + 4096);
    }
    __builtin_amdgcn_s_barrier();
    asm volatile("s_waitcnt lgkmcnt(0)" ::: "memory");
    __builtin_amdgcn_sched_barrier(0);
    __builtin_amdgcn_s_setprio(1);
#pragma unroll
    for (int mi = 0; mi < 4; ++mi)
#pragma unroll
      for (int ni = 0; ni < 4; ++ni)
        acc[mi][ni] = __builtin_amdgcn_mfma_f32_16x16x32_bf16(a1[mi], b1[ni],
                                                              acc[mi][ni], 0, 0, 0);
    __builtin_amdgcn_s_setprio(0);
    __builtin_amdgcn_sched_barrier(0);

    // ---------------- tile boundary ----------------
    // drain tile tt+1's loads (oldest 6); keep tile tt+2's 6 in flight
    if (s < NT) {
      asm volatile("s_waitcnt vmcnt(6)" ::: "memory");
    } else {
      asm volatile("s_waitcnt vmcnt(0)" ::: "memory");
    }
    __builtin_amdgcn_sched_barrier(0);
    __builtin_amdgcn_s_barrier();
    rb = (rb >= 2) ? 0 : rb + 1;
  }

  // epilogue: C/D layout: col = lane&15, row = (lane>>4)*4 + r
  const int r0 = fq * 4;
  const int growb = mb * 256 + wr * 64 + r0;
  const int gcolb = nb * 128 + wc * 64 + fr;
  if constexpr (EP == 1) {
    unsigned short* C = (unsigned short*)Cout;  // [M][N] bf16 relu(.+bias)
#pragma unroll
    for (int ni = 0; ni < 4; ++ni) {
      int col = gcolb + ni * 16;
#pragma unroll
      for (int mi = 0; mi < 4; ++mi) {
        int row = growb + mi * 16;
        f32x4 v = acc[mi][ni];
#pragma unroll
        for (int r = 0; r < 4; ++r)
          C[(size_t)(row + r) * N + col] = f2bf(fmaxf(v[r] + bv[ni], 0.0f));
      }
    }
  } else {  // EP == 3: split-K fp32 partial
    float* C = (float*)Cout + (size_t)kc * M * N;
#pragma unroll
    for (int ni = 0; ni < 4; ++ni) {
      int col = gcolb + ni * 16;
#pragma unroll
      for (int mi = 0; mi < 4; ++mi) {
        int row = growb + mi * 16;
        f32x4 v = acc[mi][ni];
#pragma unroll
        for (int r = 0; r < 4; ++r)
          C[(size_t)(row + r) * N + col] = v[r];
      }
    }
  }
}

// ------------------------------ main GEMM ----------------------------------
// (unchanged R3 2-phase kernel; used for G1/G3/G5 + fallback)
template <int EP, bool ABF16>
__global__ __launch_bounds__(256, 2)
void gemm_bt(const void* __restrict__ Av, const unsigned short* __restrict__ Bt,
             void* __restrict__ Cout, const float* __restrict__ bias,
             int M, int N, int K, int nbx, int Klen) {
  __shared__ __align__(16) unsigned short As[128 * 64];
  __shared__ __align__(16) unsigned short Bs[128 * 64];
  const int t = threadIdx.x;
  const int l = t & 63;
  const int w = t >> 6;

  int wg = blockIdx.x;
  const int cpx = gridDim.x >> 3;
  wg = (wg & 7) * cpx + (wg >> 3);
  const int mb = wg / nbx, nb = wg % nbx;
  const int kc = blockIdx.y;
  const int koff = kc * Klen;

  const int wr = w >> 1, wc = w & 1;
  f32x4 acc[4][4] = {};

  const int srow = w * 8 + (l >> 3);
  const int sk0  = 8 * ((l & 7) ^ (l >> 3));
  const unsigned short* Bg = Bt + (size_t)(nb * 128 + srow) * K + koff + sk0;
  unsigned short* BsL = Bs + w * 512 + l * 8;
  unsigned short* AsL = As + w * 512 + l * 8;

  const unsigned short* Ag16 = nullptr;
  const float* Ag32 = nullptr;
  unsigned short* AsWr = nullptr;
  int ak = 0, axm = 0;
  if constexpr (ABF16) {
    Ag16 = (const unsigned short*)Av + (size_t)(mb * 128 + srow) * K + koff + sk0;
  } else {
    const int ar = t >> 1;
    ak = (t & 1) * 32;
    axm = (ar & 7) << 3;
    Ag32 = (const float*)Av + (size_t)(mb * 128 + ar) * K + koff + ak;
    AsWr = As + ar * 64;
  }

  const int fr = l & 15, fq = l >> 4;
  const int rxor = (fr & 7) << 3;

  const int steps = Klen >> 6;
  for (int kb = 0; kb < steps; ++kb) {
#pragma unroll
    for (int i = 0; i < 4; ++i)
      gload_lds16(Bg + (size_t)i * 32 * K, BsL + i * 2048);
    Bg += 64;
    if constexpr (ABF16) {
#pragma unroll
      for (int i = 0; i < 4; ++i)
        gload_lds16(Ag16 + (size_t)i * 32 * K, AsL + i * 2048);
      Ag16 += 64;
    } else {
#pragma unroll
      for (int q = 0; q < 4; ++q) {
        float4 c0 = ((const float4*)Ag32)[q * 2];
        float4 c1 = ((const float4*)Ag32)[q * 2 + 1];
        u16x8 v;
        v[0] = f2bf(c0.x); v[1] = f2bf(c0.y); v[2] = f2bf(c0.z); v[3] = f2bf(c0.w);
        v[4] = f2bf(c1.x); v[5] = f2bf(c1.y); v[6] = f2bf(c1.z); v[7] = f2bf(c1.w);
        *(u16x8*)&AsWr[(ak + q * 8) ^ axm] = v;
      }
      Ag32 += 64;
    }
    __syncthreads();

    bf16x8 af[2][4], bfr[2][4];
#pragma unroll
    for (int kk = 0; kk < 2; ++kk) {
#pragma unroll
      for (int mi = 0; mi < 4; ++mi) {
        int arow = wr * 64 + mi * 16 + fr;
        af[kk][mi] = *(const bf16x8*)&As[arow * 64 + ((kk * 32 + fq * 8) ^ rxor)];
      }
#pragma unroll
      for (int ni = 0; ni < 4; ++ni) {
        int brow = wc * 64 + ni * 16 + fr;
        bfr[kk][ni] = *(const bf16x8*)&Bs[brow * 64 + ((kk * 32 + fq * 8) ^ rxor)];
      }
    }
#pragma unroll
    for (int kk = 0; kk < 2; ++kk)
#pragma unroll
      for (int mi = 0; mi < 4; ++mi)
#pragma unroll
        for (int ni = 0; ni < 4; ++ni)
          acc[mi][ni] = __builtin_amdgcn_mfma_f32_16x16x32_bf16(af[kk][mi], bfr[kk][ni],
                                                                acc[mi][ni], 0, 0, 0);
    __syncthreads();
  }

  const int r0 = fq * 4;
  const int c0 = fr;
  const int growb = mb * 128 + wr * 64 + r0;
  const int gcolb = nb * 128 + wc * 64 + c0;
  if constexpr (EP == 0) {
    unsigned short* Ct = (unsigned short*)Cout;  // [N][M] bf16
#pragma unroll
    for (int ni = 0; ni < 4; ++ni) {
      int col = gcolb + ni * 16;
#pragma unroll
      for (int mi = 0; mi < 4; ++mi) {
        int row = growb + mi * 16;
        f32x4 v = acc[mi][ni];
        u16x4 o;
        o[0] = f2bf(v[0]); o[1] = f2bf(v[1]); o[2] = f2bf(v[2]); o[3] = f2bf(v[3]);
        *(u16x4*)&Ct[(size_t)col * M + row] = o;
      }
    }
  } else if constexpr (EP == 1) {
    unsigned short* C = (unsigned short*)Cout;  // [M][N] bf16, relu(.+bias)
#pragma unroll
    for (int ni = 0; ni < 4; ++ni) {
      int col = gcolb + ni * 16;
      float b = bias[col];
#pragma unroll
      for (int mi = 0; mi < 4; ++mi) {
        int row = growb + mi * 16;
        f32x4 v = acc[mi][ni];
#pragma unroll
        for (int r = 0; r < 4; ++r)
          C[(size_t)(row + r) * N + col] = f2bf(fmaxf(v[r] + b, 0.0f));
      }
    }
  } else {  // EP == 3: split-K fp32 partial
    float* C = (float*)Cout + (size_t)kc * M * N;
#pragma unroll
    for (int ni = 0; ni < 4; ++ni) {
      int col = gcolb + ni * 16;
#pragma unroll
      for (int mi = 0; mi < 4; ++mi) {
        int row = growb + mi * 16;
        f32x4 v = acc[mi][ni];
#pragma unroll
        for (int r = 0; r < 4; ++r)
          C[(size_t)(row + r) * N + col] = v[r];
      }
    }
  }
}

// ------------------------------ head kernel --------------------------------
__global__ __launch_bounds__(256, 2)
void head_kernel(const unsigned short* __restrict__ EMB, const int* __restrict__ tf,
                 const int* __restrict__ gi, const unsigned short* __restrict__ Wh1t,
                 const float* __restrict__ bh1, const float* __restrict__ Wh2,
                 const float* __restrict__ bh2, float* __restrict__ out, int P) {
  __shared__ __align__(16) union SU {
    struct { unsigned short As[64 * 64]; unsigned short Bs[256 * 64]; } s;
    unsigned short hdn[64 * 264];
  } u;
  __shared__ float wh2s[256 * 3];
  const int t = threadIdx.x, l = t & 63, w = t >> 6;
  const int pb = blockIdx.x;

  wh2s[t]       = Wh2[t];
  wh2s[t + 256] = Wh2[t + 256];
  wh2s[t + 512] = Wh2[t + 512];

  const int srow = w * 8 + (l >> 3);
  const int sk0  = 8 * ((l & 7) ^ (l >> 3));
  size_t tfo[2], gio[2];
#pragma unroll
  for (int i = 0; i < 2; ++i) {
    int p = pb * 64 + i * 32 + srow;
    if (p >= P) p = P - 1;
    tfo[i] = (size_t)tf[p] * 256;
    gio[i] = (size_t)gi[p] * 256;
  }
  const unsigned short* BgB = Wh1t + (size_t)srow * 512 + sk0;
  unsigned short* AsL = u.s.As + w * 512 + l * 8;
  unsigned short* BsL = u.s.Bs + w * 512 + l * 8;

  const int fr = l & 15, fq = l >> 4;
  const int rxor = (fr & 7) << 3;

  f32x4 acc[4][4] = {};
  for (int kb = 0; kb < 8; ++kb) {
    const int klo = (kb & 3) * 64 + sk0;
#pragma unroll
    for (int i = 0; i < 2; ++i)
      gload_lds16(EMB + ((kb < 4) ? tfo[i] : gio[i]) + klo, AsL + i * 2048);
#pragma unroll
    for (int i = 0; i < 8; ++i)
      gload_lds16(BgB + (size_t)i * 32 * 512 + kb * 64, BsL + i * 2048);
    __syncthreads();

    bf16x8 af[2][4], bfr[2][4];
#pragma unroll
    for (int kk = 0; kk < 2; ++kk) {
#pragma unroll
      for (int mi = 0; mi < 4; ++mi) {
        int arow = mi * 16 + fr;
        af[kk][mi] = *(const bf16x8*)&u.s.As[arow * 64 + ((kk * 32 + fq * 8) ^ rxor)];
      }
#pragma unroll
      for (int ni = 0; ni < 4; ++ni) {
        int brow = w * 64 + ni * 16 + fr;
        bfr[kk][ni] = *(const bf16x8*)&u.s.Bs[brow * 64 + ((kk * 32 + fq * 8) ^ rxor)];
      }
    }
#pragma unroll
    for (int kk = 0; kk < 2; ++kk)
#pragma unroll
      for (int mi = 0; mi < 4; ++mi)
#pragma unroll
        for (int ni = 0; ni < 4; ++ni)
          acc[mi][ni] = __builtin_amdgcn_mfma_f32_16x16x32_bf16(af[kk][mi], bfr[kk][ni],
                                                                acc[mi][ni], 0, 0, 0);
    __syncthreads();
  }

  const int r0 = fq * 4, c0 = fr;
#pragma unroll
  for (int ni = 0; ni < 4; ++ni) {
    int col = w * 64 + ni * 16 + c0;
    float b = bh1[col];
#pragma unroll
    for (int mi = 0; mi < 4; ++mi) {
      int row = mi * 16 + r0;
      f32x4 v = acc[mi][ni];
#pragma unroll
      for (int r = 0; r < 4; ++r) {
        float xv = v[r] + b;
        float g = 0.5f * xv * (1.0f + erff(xv * 0.70710678118f));
        u.hdn[(row + r) * 264 + col] = f2bf(g);
      }
    }
  }
  __syncthreads();

  const int pl = w * 16 + (l >> 2);
  const int pg = pb * 64 + pl;
  const int ks = (l & 3) * 64;
  float a0 = 0.f, a1 = 0.f, a2 = 0.f;
  const unsigned short* hr = u.hdn + pl * 264 + ks;
#pragma unroll
  for (int kq = 0; kq < 8; ++kq) {
    u16x8 hv = *(const u16x8*)(hr + kq * 8);
#pragma unroll
    for (int j = 0; j < 8; ++j) {
      float h = bf2f(hv[j]);
      int k = ks + kq * 8 + j;
      a0 = fmaf(h, wh2s[k * 3 + 0], a0);
      a1 = fmaf(h, wh2s[k * 3 + 1], a1);
      a2 = fmaf(h, wh2s[k * 3 + 2], a2);
    }
  }
  a0 += __shfl_xor(a0, 1); a0 += __shfl_xor(a0, 2);
  a1 += __shfl_xor(a1, 1); a1 += __shfl_xor(a1, 2);
  a2 += __shfl_xor(a2, 1); a2 += __shfl_xor(a2, 2);
  if ((l & 3) == 0 && pg < P) {
    out[(size_t)pg * 3 + 0] = a0 + bh2[0];
    out[(size_t)pg * 3 + 1] = a1 + bh2[1];
    out[(size_t)pg * 3 + 2] = a2 + bh2[2];
  }
}

// ------------------------------- launcher ----------------------------------

extern "C" void kernel_launch(void* const* d_in, const int* in_sizes, int n_in,
                              void* d_out, int out_size, void* d_ws, size_t ws_size,
                              hipStream_t stream) {
  const float* x   = (const float*)d_in[0];
  const float* adj = (const float*)d_in[1];
  const int*   tf  = (const int*)d_in[2];
  const int*   gi  = (const int*)d_in[3];
  const float* W0  = (const float*)d_in[4];
  const float* b0  = (const float*)d_in[5];
  const float* W1  = (const float*)d_in[6];
  const float* b1  = (const float*)d_in[7];
  const float* W2  = (const float*)d_in[8];
  const float* b2  = (const float*)d_in[9];
  const float* Wh1 = (const float*)d_in[10];
  const float* bh1 = (const float*)d_in[11];
  const float* Wh2 = (const float*)d_in[12];
  const float* bh2 = (const float*)d_in[13];
  float* out = (float*)d_out;

  const int NN = 16384;
  const int P = in_sizes[2];  // 100000

  char* ws = (char*)d_ws;
  size_t off = 0;
  auto alloc = [&](size_t bytes) -> char* {
    char* p = ws + off;
    off += (bytes + 255) & ~(size_t)255;
    return p;
  };
  unsigned short* W0t  = (unsigned short*)alloc((size_t)512 * 1024 * 2);
  unsigned short* W1t  = (unsigned short*)alloc((size_t)512 * 512 * 2);
  unsigned short* W2t  = (unsigned short*)alloc((size_t)256 * 512 * 2);
  unsigned short* Wh1t = (unsigned short*)alloc((size_t)256 * 512 * 2);
  unsigned short* Tt   = (unsigned short*)alloc((size_t)512 * NN * 2);  // T0t/T1t/T2t
  unsigned short* H    = (unsigned short*)alloc((size_t)NN * 512 * 2);  // H0/H1 bf16
  unsigned short* EMB  = (unsigned short*)alloc((size_t)NN * 256 * 2);
  float*          Pp   = (float*)alloc((size_t)2 * NN * 256 * 4);       // split-K partials
  size_t base_end = off;

  bool useAdjB = false;
  unsigned short* adjb = nullptr;
  if (ws_size >= base_end + (size_t)NN * NN * 2) {
    adjb = (unsigned short*)alloc((size_t)NN * NN * 2);
    useAdjB = true;
  }

  // weight transpose+convert (tiny)
  tcvt_kernel<<<dim3((1024 * 512 + 255) / 256), 256, 0, stream>>>(W0, W0t, 1024, 512);
  tcvt_kernel<<<dim3((512 * 512 + 255) / 256), 256, 0, stream>>>(W1, W1t, 512, 512);
  tcvt_kernel<<<dim3((512 * 256 + 255) / 256), 256, 0, stream>>>(W2, W2t, 512, 256);
  tcvt_kernel<<<dim3((512 * 256 + 255) / 256), 256, 0, stream>>>(Wh1, Wh1t, 512, 256);
  if (useAdjB)
    cvt_bf16_kernel<<<4096, 256, 0, stream>>>(adj, adjb, (size_t)NN * NN);

  // G1: T0t = (x @ W0)^T                       [512][16384] bf16
  gemm_bt<0, false><<<dim3(512), 256, 0, stream>>>(x, W0t, Tt, nullptr,
                                                   NN, 512, 1024, 4, 1024);
  // G2: H0 = relu(adj @ T0 + b0)               [16384][512] bf16
  if (useAdjB)
    gemm8p<1><<<dim3(256), 512, 0, stream>>>(adjb, Tt, H, b0, NN, 512, NN, 4, NN);
  else
    gemm_bt<1, false><<<dim3(512), 256, 0, stream>>>(adj, Tt, H, b0,
                                                     NN, 512, NN, 4, NN);
  // G3: T1t = (H0 @ W1)^T
  gemm_bt<0, true><<<dim3(512), 256, 0, stream>>>(H, W1t, Tt, nullptr,
                                                  NN, 512, 512, 4, 512);
  // G4: H1 = relu(adj @ T1 + b1)
  if (useAdjB)
    gemm8p<1><<<dim3(256), 512, 0, stream>>>(adjb, Tt, H, b1, NN, 512, NN, 4, NN);
  else
    gemm_bt<1, false><<<dim3(512), 256, 0, stream>>>(adj, Tt, H, b1,
                                                     NN, 512, NN, 4, NN);
  // G5: T2t = (H1 @ W2)^T                      [256][16384] bf16
  gemm_bt<0, true><<<dim3(256), 256, 0, stream>>>(H, W2t, Tt, nullptr,
                                                  NN, 256, 512, 2, 512);
  // G6: Pp[kc] = adj[:, kc] @ T2[kc, :]        split-K=2 fp32 partials
  if (useAdjB)
    gemm8p<3><<<dim3(128, 2), 512, 0, stream>>>(adjb, Tt, Pp, nullptr,
                                                NN, 256, NN, 2, NN / 2);
  else
    gemm_bt<3, false><<<dim3(256, 2), 256, 0, stream>>>(adj, Tt, Pp, nullptr,
                                                        NN, 256, NN, 2, NN / 2);
  // EMB = Pp[0] + Pp[1] + b2                   [16384][256] bf16
  reduce2_kernel<<<dim3(4096), 256, 0, stream>>>(Pp, b2, EMB, NN * 256, 256);
  // head: gather + MLP + logits
  head_kernel<<<dim3((P + 63) / 64), 256, 0, stream>>>(EMB, tf, gi, Wh1t, bh1,
                                                       Wh2, bh2, out, P);
}

// Round 5
// 1288.909 us; speedup vs baseline: 1.0709x; 1.0709x over previous
//
#include <hip/hip_runtime.h>
#include <hip/hip_bf16.h>
#include <stdint.h>

// ---------------------------------------------------------------------------
// ScRegNet GCN pretrainer fused pipeline, MI355X / gfx950.  Round 5.
// h0 = relu(adj@(x@W0)+b0); h1 = relu(adj@(h0@W1)+b1); emb = adj@(h1@W2)+b2
// logits = gelu(concat(emb[tf],emb[gene])@Wh1+bh1)@Wh2+bh2
//
// R4 post-mortem: 256x128/8-wave gemm8p was LDS-read-bound (per-wave 64x64
// -> 2.0 MFMA:ds_read, per-CU 1536 read-cyc > 1240 MFMA-cyc). Fix: per-wave
// 128x64 (m201 geometry).
// R5: gemm256 = BM=BN=256, 8 waves (2Mx4N), BK=32, 4-deep LDS ring (128 KiB),
// derived counted vmcnt(8/4/0) boundaries, setprio MFMA clusters, linear LDS
// (64B rows are bank-floor for this read pattern - no swizzle needed).
// G2/G4 split-K=2, G6 split-K=4 (grid 256 blocks = full GPU) + fused
// reduce(+bias,+relu) kernels.  G1/G3/G5/cvt/head unchanged.
// ---------------------------------------------------------------------------

using f32x4  = __attribute__((ext_vector_type(4))) float;
using bf16x8 = __attribute__((ext_vector_type(8))) __bf16;
using u16x8  = __attribute__((ext_vector_type(8))) unsigned short;
using u16x4  = __attribute__((ext_vector_type(4))) unsigned short;

static __device__ __forceinline__ unsigned short f2bf(float f) {
  unsigned u = __builtin_bit_cast(unsigned, f);
  u += 0x7FFFu + ((u >> 16) & 1u);           // RNE (finite inputs only)
  return (unsigned short)(u >> 16);
}
static __device__ __forceinline__ float bf2f(unsigned short h) {
  unsigned u = ((unsigned)h) << 16;
  return __builtin_bit_cast(float, u);
}
// async global->LDS, 16 B per lane. LDS dest: wave-uniform base + lane*16.
static __device__ __forceinline__ void gload_lds16(const void* g, void* l) {
  __builtin_amdgcn_global_load_lds((__attribute__((address_space(1))) void*)(void*)g,
                                   (__attribute__((address_space(3))) void*)l,
                                   16, 0, 0);
}

// --------------------------- small converters ------------------------------

// out[nf][k] = bf16(in[k][nf])   (weights: [K][Nf] fp32 -> [Nf][K] bf16)
__global__ void tcvt_kernel(const float* __restrict__ in,
                            unsigned short* __restrict__ outp, int K, int Nf) {
  int id = blockIdx.x * 256 + threadIdx.x;
  if (id >= K * Nf) return;
  int k = id % K, nf = id / K;
  outp[id] = f2bf(in[(size_t)k * Nf + nf]);
}

// flat fp32 -> bf16 (adj copy), vectorized 8/thread
__global__ void cvt_bf16_kernel(const float* __restrict__ in,
                                unsigned short* __restrict__ outp, size_t n) {
  size_t i = ((size_t)blockIdx.x * blockDim.x + threadIdx.x) * 8;
  size_t stride = (size_t)gridDim.x * blockDim.x * 8;
  for (; i + 8 <= n; i += stride) {
    const float4* p = (const float4*)(in + i);
    float4 a = p[0], b = p[1];
    u16x8 v;
    v[0] = f2bf(a.x); v[1] = f2bf(a.y); v[2] = f2bf(a.z); v[3] = f2bf(a.w);
    v[4] = f2bf(b.x); v[5] = f2bf(b.y); v[6] = f2bf(b.z); v[7] = f2bf(b.w);
    *(u16x8*)(outp + i) = v;
  }
}

// split-K reduce + bias (+relu) -> bf16
template <int NPART, bool RELU>
__global__ void reduceK_kernel(const float* __restrict__ Pp, const float* __restrict__ bias,
                               unsigned short* __restrict__ outp, int MN, int Nmask) {
  int i = (blockIdx.x * 256 + threadIdx.x) * 4;
  if (i >= MN) return;
  float4 s = *(const float4*)(Pp + i);
#pragma unroll
  for (int p = 1; p < NPART; ++p) {
    float4 v = *(const float4*)(Pp + (size_t)p * MN + i);
    s.x += v.x; s.y += v.y; s.z += v.z; s.w += v.w;
  }
  int col = i & Nmask;
  float r0 = s.x + bias[col + 0];
  float r1 = s.y + bias[col + 1];
  float r2 = s.z + bias[col + 2];
  float r3 = s.w + bias[col + 3];
  if (RELU) {
    r0 = fmaxf(r0, 0.0f); r1 = fmaxf(r1, 0.0f);
    r2 = fmaxf(r2, 0.0f); r3 = fmaxf(r3, 0.0f);
  }
  u16x4 o;
  o[0] = f2bf(r0); o[1] = f2bf(r1); o[2] = f2bf(r2); o[3] = f2bf(r3);
  *(u16x4*)(outp + i) = o;
}

// ---------------- deep-pipelined 256x256 adj GEMM (gemm256) ----------------
// Pp[kc] += A(Mx[koff..koff+Klen)) * Bt(Nx...)^T partials (fp32).
// A bf16 [M][K] (adjb), Bt bf16 [N][K].  BM=BN=256, BK=32.
// 512 thr = 8 waves (2M x 4N), per-wave 128x64 = 8x4 frags 16x16x32 (MFMA:
// ds_read = 2.67 -> MFMA-bound per CU).
// LDS: 4-deep ring, per tile A 256x32 (16K) + B 256x32 (16K) -> 128 KiB.
// Linear layout (64B rows): read pattern (16 rows x 4 k-slots) hits the
// 128 B/cyc LDS floor without swizzle (addr mod 128 = (fr&1)*64 + fq*16).
// Staging: 4 gload_lds16 per tile (2 A + 2 B); stage tile t+3 during t.
// Boundary: vmcnt(8) steady (drain t+1, keep t+2/t+3 in flight); 4/0 tail.
__global__ __launch_bounds__(512, 1)
void gemm256(const unsigned short* __restrict__ A, const unsigned short* __restrict__ Bt,
             float* __restrict__ Pp, int M, int N, int K, int nbx, int Klen) {
  __shared__ __align__(16) unsigned short As[4 * 256 * 32];  // 64 KiB
  __shared__ __align__(16) unsigned short Bs[4 * 256 * 32];  // 64 KiB
  const int t = threadIdx.x, l = t & 63, w = t >> 6;

  int wg = blockIdx.x;
  const int cpx = gridDim.x >> 3;              // gridDim.x % 8 == 0
  wg = (wg & 7) * cpx + (wg >> 3);
  const int mb = wg / nbx, nb = wg % nbx;
  const int kc = blockIdx.y;
  const int koff = kc * Klen;
  const int wr = w >> 2, wc = w & 3;           // 2M x 4N wave grid
  const int fr = l & 15, fq = l >> 4;

  // staging: instr j covers rows j*128 + (t>>2), k-slot t&3
  const int srow = t >> 2;
  const int sk0  = (t & 3) * 8;
  const unsigned short* AgR = A  + (size_t)(mb * 256 + srow) * K + koff + sk0;
  const unsigned short* BgR = Bt + (size_t)(nb * 256 + srow) * K + koff + sk0;
  unsigned short* AsL = As + t * 8;
  unsigned short* BsL = Bs + t * 8;

  const int NT = Klen >> 5;

  // prologue: stage tiles 0,1,2 (tile-major issue order for vmcnt counting)
#pragma unroll
  for (int s = 0; s < 3; ++s) {
    gload_lds16(AgR + s * 32, AsL + s * 8192);
    gload_lds16(AgR + (size_t)128 * K + s * 32, AsL + s * 8192 + 4096);
    gload_lds16(BgR + s * 32, BsL + s * 8192);
    gload_lds16(BgR + (size_t)128 * K + s * 32, BsL + s * 8192 + 4096);
  }
  asm volatile("s_waitcnt vmcnt(8)" ::: "memory");  // tile 0's 4 drained
  __builtin_amdgcn_sched_barrier(0);
  __builtin_amdgcn_s_barrier();

  f32x4 acc[8][4] = {};
  for (int tt = 0; tt < NT; ++tt) {
    const int buf = tt & 3;
    const int sb  = (tt + 3) & 3;
    const unsigned short* Ab = As + buf * 8192;
    const unsigned short* Bb = Bs + buf * 8192;
    const bool stg = (tt + 3) < NT;
    const unsigned short* AgS = AgR + (size_t)(tt + 3) * 32;
    const unsigned short* BgS = BgR + (size_t)(tt + 3) * 32;

    // -------- phase 0: B-frags (4) + A-frags mi0..3 (4); stage A[t+3] ------
    bf16x8 bfr[4], af[4];
#pragma unroll
    for (int ni = 0; ni < 4; ++ni)
      bfr[ni] = *(const bf16x8*)&Bb[(wc * 64 + ni * 16 + fr) * 32 + fq * 8];
#pragma unroll
    for (int mi = 0; mi < 4; ++mi)
      af[mi] = *(const bf16x8*)&Ab[(wr * 128 + mi * 16 + fr) * 32 + fq * 8];
    if (stg) {
      gload_lds16(AgS, AsL + sb * 8192);
      gload_lds16(AgS + (size_t)128 * K, AsL + sb * 8192 + 4096);
    }
    __builtin_amdgcn_sched_barrier(0);
    __builtin_amdgcn_s_barrier();
    asm volatile("s_waitcnt lgkmcnt(0)" ::: "memory");
    __builtin_amdgcn_sched_barrier(0);
    __builtin_amdgcn_s_setprio(1);
#pragma unroll
    for (int mi = 0; mi < 4; ++mi)
#pragma unroll
      for (int ni = 0; ni < 4; ++ni)
        acc[mi][ni] = __builtin_amdgcn_mfma_f32_16x16x32_bf16(af[mi], bfr[ni],
                                                              acc[mi][ni], 0, 0, 0);
    __builtin_amdgcn_s_setprio(0);
    __builtin_amdgcn_sched_barrier(0);
    __builtin_amdgcn_s_barrier();

    // -------- phase 1: A-frags mi4..7 (4); stage B[t+3] --------------------
    bf16x8 ag[4];
#pragma unroll
    for (int mi = 0; mi < 4; ++mi)
      ag[mi] = *(const bf16x8*)&Ab[(wr * 128 + (mi + 4) * 16 + fr) * 32 + fq * 8];
    if (stg) {
      gload_lds16(BgS, BsL + sb * 8192);
      gload_lds16(BgS + (size_t)128 * K, BsL + sb * 8192 + 4096);
    }
    __builtin_amdgcn_sched_barrier(0);
    __builtin_amdgcn_s_barrier();
    asm volatile("s_waitcnt lgkmcnt(0)" ::: "memory");
    __builtin_amdgcn_sched_barrier(0);
    __builtin_amdgcn_s_setprio(1);
#pragma unroll
    for (int mi = 0; mi < 4; ++mi)
#pragma unroll
      for (int ni = 0; ni < 4; ++ni)
        acc[mi + 4][ni] = __builtin_amdgcn_mfma_f32_16x16x32_bf16(ag[mi], bfr[ni],
                                                                  acc[mi + 4][ni], 0, 0, 0);
    __builtin_amdgcn_s_setprio(0);
    __builtin_amdgcn_sched_barrier(0);

    // -------- tile boundary: derived counted wait --------------------------
    // in-flight after this drain: tiles tt+2..min(NT-1,tt+3)
    if (tt + 4 <= NT) {
      asm volatile("s_waitcnt vmcnt(8)" ::: "memory");
    } else if (tt + 3 == NT) {
      asm volatile("s_waitcnt vmcnt(4)" ::: "memory");
    } else {
      asm volatile("s_waitcnt vmcnt(0)" ::: "memory");
    }
    __builtin_amdgcn_sched_barrier(0);
    __builtin_amdgcn_s_barrier();
  }

  // epilogue: fp32 partial write. C/D layout: col = lane&15, row=(lane>>4)*4+r
  float* C = Pp + (size_t)kc * M * N;
  const int growb = mb * 256 + wr * 128 + fq * 4;
  const int gcolb = nb * 256 + wc * 64 + fr;
#pragma unroll
  for (int mi = 0; mi < 8; ++mi) {
    int row = growb + mi * 16;
#pragma unroll
    for (int ni = 0; ni < 4; ++ni) {
      int col = gcolb + ni * 16;
      f32x4 v = acc[mi][ni];
#pragma unroll
      for (int r = 0; r < 4; ++r)
        C[(size_t)(row + r) * N + col] = v[r];
    }
  }
}

// ------------------------------ main GEMM ----------------------------------
// (unchanged R3 2-phase kernel; used for G1/G3/G5 + no-adjb fallback)
template <int EP, bool ABF16>
__global__ __launch_bounds__(256, 2)
void gemm_bt(const void* __restrict__ Av, const unsigned short* __restrict__ Bt,
             void* __restrict__ Cout, const float* __restrict__ bias,
             int M, int N, int K, int nbx, int Klen) {
  __shared__ __align__(16) unsigned short As[128 * 64];
  __shared__ __align__(16) unsigned short Bs[128 * 64];
  const int t = threadIdx.x;
  const int l = t & 63;
  const int w = t >> 6;

  int wg = blockIdx.x;
  const int cpx = gridDim.x >> 3;
  wg = (wg & 7) * cpx + (wg >> 3);
  const int mb = wg / nbx, nb = wg % nbx;
  const int kc = blockIdx.y;
  const int koff = kc * Klen;

  const int wr = w >> 1, wc = w & 1;
  f32x4 acc[4][4] = {};

  const int srow = w * 8 + (l >> 3);
  const int sk0  = 8 * ((l & 7) ^ (l >> 3));
  const unsigned short* Bg = Bt + (size_t)(nb * 128 + srow) * K + koff + sk0;
  unsigned short* BsL = Bs + w * 512 + l * 8;
  unsigned short* AsL = As + w * 512 + l * 8;

  const unsigned short* Ag16 = nullptr;
  const float* Ag32 = nullptr;
  unsigned short* AsWr = nullptr;
  int ak = 0, axm = 0;
  if constexpr (ABF16) {
    Ag16 = (const unsigned short*)Av + (size_t)(mb * 128 + srow) * K + koff + sk0;
  } else {
    const int ar = t >> 1;
    ak = (t & 1) * 32;
    axm = (ar & 7) << 3;
    Ag32 = (const float*)Av + (size_t)(mb * 128 + ar) * K + koff + ak;
    AsWr = As + ar * 64;
  }

  const int fr = l & 15, fq = l >> 4;
  const int rxor = (fr & 7) << 3;

  const int steps = Klen >> 6;
  for (int kb = 0; kb < steps; ++kb) {
#pragma unroll
    for (int i = 0; i < 4; ++i)
      gload_lds16(Bg + (size_t)i * 32 * K, BsL + i * 2048);
    Bg += 64;
    if constexpr (ABF16) {
#pragma unroll
      for (int i = 0; i < 4; ++i)
        gload_lds16(Ag16 + (size_t)i * 32 * K, AsL + i * 2048);
      Ag16 += 64;
    } else {
#pragma unroll
      for (int q = 0; q < 4; ++q) {
        float4 c0 = ((const float4*)Ag32)[q * 2];
        float4 c1 = ((const float4*)Ag32)[q * 2 + 1];
        u16x8 v;
        v[0] = f2bf(c0.x); v[1] = f2bf(c0.y); v[2] = f2bf(c0.z); v[3] = f2bf(c0.w);
        v[4] = f2bf(c1.x); v[5] = f2bf(c1.y); v[6] = f2bf(c1.z); v[7] = f2bf(c1.w);
        *(u16x8*)&AsWr[(ak + q * 8) ^ axm] = v;
      }
      Ag32 += 64;
    }
    __syncthreads();

    bf16x8 af[2][4], bfr[2][4];
#pragma unroll
    for (int kk = 0; kk < 2; ++kk) {
#pragma unroll
      for (int mi = 0; mi < 4; ++mi) {
        int arow = wr * 64 + mi * 16 + fr;
        af[kk][mi] = *(const bf16x8*)&As[arow * 64 + ((kk * 32 + fq * 8) ^ rxor)];
      }
#pragma unroll
      for (int ni = 0; ni < 4; ++ni) {
        int brow = wc * 64 + ni * 16 + fr;
        bfr[kk][ni] = *(const bf16x8*)&Bs[brow * 64 + ((kk * 32 + fq * 8) ^ rxor)];
      }
    }
#pragma unroll
    for (int kk = 0; kk < 2; ++kk)
#pragma unroll
      for (int mi = 0; mi < 4; ++mi)
#pragma unroll
        for (int ni = 0; ni < 4; ++ni)
          acc[mi][ni] = __builtin_amdgcn_mfma_f32_16x16x32_bf16(af[kk][mi], bfr[kk][ni],
                                                                acc[mi][ni], 0, 0, 0);
    __syncthreads();
  }

  const int r0 = fq * 4;
  const int c0 = fr;
  const int growb = mb * 128 + wr * 64 + r0;
  const int gcolb = nb * 128 + wc * 64 + c0;
  if constexpr (EP == 0) {
    unsigned short* Ct = (unsigned short*)Cout;  // [N][M] bf16
#pragma unroll
    for (int ni = 0; ni < 4; ++ni) {
      int col = gcolb + ni * 16;
#pragma unroll
      for (int mi = 0; mi < 4; ++mi) {
        int row = growb + mi * 16;
        f32x4 v = acc[mi][ni];
        u16x4 o;
        o[0] = f2bf(v[0]); o[1] = f2bf(v[1]); o[2] = f2bf(v[2]); o[3] = f2bf(v[3]);
        *(u16x4*)&Ct[(size_t)col * M + row] = o;
      }
    }
  } else if constexpr (EP == 1) {
    unsigned short* C = (unsigned short*)Cout;  // [M][N] bf16, relu(.+bias)
#pragma unroll
    for (int ni = 0; ni < 4; ++ni) {
      int col = gcolb + ni * 16;
      float b = bias[col];
#pragma unroll
      for (int mi = 0; mi < 4; ++mi) {
        int row = growb + mi * 16;
        f32x4 v = acc[mi][ni];
#pragma unroll
        for (int r = 0; r < 4; ++r)
          C[(size_t)(row + r) * N + col] = f2bf(fmaxf(v[r] + b, 0.0f));
      }
    }
  } else {  // EP == 3: split-K fp32 partial
    float* C = (float*)Cout + (size_t)kc * M * N;
#pragma unroll
    for (int ni = 0; ni < 4; ++ni) {
      int col = gcolb + ni * 16;
#pragma unroll
      for (int mi = 0; mi < 4; ++mi) {
        int row = growb + mi * 16;
        f32x4 v = acc[mi][ni];
#pragma unroll
        for (int r = 0; r < 4; ++r)
          C[(size_t)(row + r) * N + col] = v[r];
      }
    }
  }
}

// ------------------------------ head kernel --------------------------------
__global__ __launch_bounds__(256, 2)
void head_kernel(const unsigned short* __restrict__ EMB, const int* __restrict__ tf,
                 const int* __restrict__ gi, const unsigned short* __restrict__ Wh1t,
                 const float* __restrict__ bh1, const float* __restrict__ Wh2,
                 const float* __restrict__ bh2, float* __restrict__ out, int P) {
  __shared__ __align__(16) union SU {
    struct { unsigned short As[64 * 64]; unsigned short Bs[256 * 64]; } s;
    unsigned short hdn[64 * 264];
  } u;
  __shared__ float wh2s[256 * 3];
  const int t = threadIdx.x, l = t & 63, w = t >> 6;
  const int pb = blockIdx.x;

  wh2s[t]       = Wh2[t];
  wh2s[t + 256] = Wh2[t + 256];
  wh2s[t + 512] = Wh2[t + 512];

  const int srow = w * 8 + (l >> 3);
  const int sk0  = 8 * ((l & 7) ^ (l >> 3));
  size_t tfo[2], gio[2];
#pragma unroll
  for (int i = 0; i < 2; ++i) {
    int p = pb * 64 + i * 32 + srow;
    if (p >= P) p = P - 1;
    tfo[i] = (size_t)tf[p] * 256;
    gio[i] = (size_t)gi[p] * 256;
  }
  const unsigned short* BgB = Wh1t + (size_t)srow * 512 + sk0;
  unsigned short* AsL = u.s.As + w * 512 + l * 8;
  unsigned short* BsL = u.s.Bs + w * 512 + l * 8;

  const int fr = l & 15, fq = l >> 4;
  const int rxor = (fr & 7) << 3;

  f32x4 acc[4][4] = {};
  for (int kb = 0; kb < 8; ++kb) {
    const int klo = (kb & 3) * 64 + sk0;
#pragma unroll
    for (int i = 0; i < 2; ++i)
      gload_lds16(EMB + ((kb < 4) ? tfo[i] : gio[i]) + klo, AsL + i * 2048);
#pragma unroll
    for (int i = 0; i < 8; ++i)
      gload_lds16(BgB + (size_t)i * 32 * 512 + kb * 64, BsL + i * 2048);
    __syncthreads();

    bf16x8 af[2][4], bfr[2][4];
#pragma unroll
    for (int kk = 0; kk < 2; ++kk) {
#pragma unroll
      for (int mi = 0; mi < 4; ++mi) {
        int arow = mi * 16 + fr;
        af[kk][mi] = *(const bf16x8*)&u.s.As[arow * 64 + ((kk * 32 + fq * 8) ^ rxor)];
      }
#pragma unroll
      for (int ni = 0; ni < 4; ++ni) {
        int brow = w * 64 + ni * 16 + fr;
        bfr[kk][ni] = *(const bf16x8*)&u.s.Bs[brow * 64 + ((kk * 32 + fq * 8) ^ rxor)];
      }
    }
#pragma unroll
    for (int kk = 0; kk < 2; ++kk)
#pragma unroll
      for (int mi = 0; mi < 4; ++mi)
#pragma unroll
        for (int ni = 0; ni < 4; ++ni)
          acc[mi][ni] = __builtin_amdgcn_mfma_f32_16x16x32_bf16(af[kk][mi], bfr[kk][ni],
                                                                acc[mi][ni], 0, 0, 0);
    __syncthreads();
  }

  const int r0 = fq * 4, c0 = fr;
#pragma unroll
  for (int ni = 0; ni < 4; ++ni) {
    int col = w * 64 + ni * 16 + c0;
    float b = bh1[col];
#pragma unroll
    for (int mi = 0; mi < 4; ++mi) {
      int row = mi * 16 + r0;
      f32x4 v = acc[mi][ni];
#pragma unroll
      for (int r = 0; r < 4; ++r) {
        float xv = v[r] + b;
        float g = 0.5f * xv * (1.0f + erff(xv * 0.70710678118f));
        u.hdn[(row + r) * 264 + col] = f2bf(g);
      }
    }
  }
  __syncthreads();

  const int pl = w * 16 + (l >> 2);
  const int pg = pb * 64 + pl;
  const int ks = (l & 3) * 64;
  float a0 = 0.f, a1 = 0.f, a2 = 0.f;
  const unsigned short* hr = u.hdn + pl * 264 + ks;
#pragma unroll
  for (int kq = 0; kq < 8; ++kq) {
    u16x8 hv = *(const u16x8*)(hr + kq * 8);
#pragma unroll
    for (int j = 0; j < 8; ++j) {
      float h = bf2f(hv[j]);
      int k = ks + kq * 8 + j;
      a0 = fmaf(h, wh2s[k * 3 + 0], a0);
      a1 = fmaf(h, wh2s[k * 3 + 1], a1);
      a2 = fmaf(h, wh2s[k * 3 + 2], a2);
    }
  }
  a0 += __shfl_xor(a0, 1); a0 += __shfl_xor(a0, 2);
  a1 += __shfl_xor(a1, 1); a1 += __shfl_xor(a1, 2);
  a2 += __shfl_xor(a2, 1); a2 += __shfl_xor(a2, 2);
  if ((l & 3) == 0 && pg < P) {
    out[(size_t)pg * 3 + 0] = a0 + bh2[0];
    out[(size_t)pg * 3 + 1] = a1 + bh2[1];
    out[(size_t)pg * 3 + 2] = a2 + bh2[2];
  }
}

// ------------------------------- launcher ----------------------------------

extern "C" void kernel_launch(void* const* d_in, const int* in_sizes, int n_in,
                              void* d_out, int out_size, void* d_ws, size_t ws_size,
                              hipStream_t stream) {
  const float* x   = (const float*)d_in[0];
  const float* adj = (const float*)d_in[1];
  const int*   tf  = (const int*)d_in[2];
  const int*   gi  = (const int*)d_in[3];
  const float* W0  = (const float*)d_in[4];
  const float* b0  = (const float*)d_in[5];
  const float* W1  = (const float*)d_in[6];
  const float* b1  = (const float*)d_in[7];
  const float* W2  = (const float*)d_in[8];
  const float* b2  = (const float*)d_in[9];
  const float* Wh1 = (const float*)d_in[10];
  const float* bh1 = (const float*)d_in[11];
  const float* Wh2 = (const float*)d_in[12];
  const float* bh2 = (const float*)d_in[13];
  float* out = (float*)d_out;

  const int NN = 16384;
  const int P = in_sizes[2];  // 100000

  char* ws = (char*)d_ws;
  size_t off = 0;
  auto alloc = [&](size_t bytes) -> char* {
    char* p = ws + off;
    off += (bytes + 255) & ~(size_t)255;
    return p;
  };
  unsigned short* W0t  = (unsigned short*)alloc((size_t)512 * 1024 * 2);
  unsigned short* W1t  = (unsigned short*)alloc((size_t)512 * 512 * 2);
  unsigned short* W2t  = (unsigned short*)alloc((size_t)256 * 512 * 2);
  unsigned short* Wh1t = (unsigned short*)alloc((size_t)256 * 512 * 2);
  unsigned short* Tt   = (unsigned short*)alloc((size_t)512 * NN * 2);  // T0t/T1t/T2t
  unsigned short* H    = (unsigned short*)alloc((size_t)NN * 512 * 2);  // H0/H1 bf16
  unsigned short* EMB  = (unsigned short*)alloc((size_t)NN * 256 * 2);
  float*          Pp   = (float*)alloc((size_t)2 * NN * 512 * 4);       // split-K partials (64 MiB)
  size_t base_end = off;

  bool useAdjB = false;
  unsigned short* adjb = nullptr;
  if (ws_size >= base_end + (size_t)NN * NN * 2) {
    adjb = (unsigned short*)alloc((size_t)NN * NN * 2);
    useAdjB = true;
  }

  // weight transpose+convert (tiny)
  tcvt_kernel<<<dim3((1024 * 512 + 255) / 256), 256, 0, stream>>>(W0, W0t, 1024, 512);
  tcvt_kernel<<<dim3((512 * 512 + 255) / 256), 256, 0, stream>>>(W1, W1t, 512, 512);
  tcvt_kernel<<<dim3((512 * 256 + 255) / 256), 256, 0, stream>>>(W2, W2t, 512, 256);
  tcvt_kernel<<<dim3((512 * 256 + 255) / 256), 256, 0, stream>>>(Wh1, Wh1t, 512, 256);
  if (useAdjB)
    cvt_bf16_kernel<<<4096, 256, 0, stream>>>(adj, adjb, (size_t)NN * NN);

  // G1: T0t = (x @ W0)^T                       [512][16384] bf16
  gemm_bt<0, false><<<dim3(512), 256, 0, stream>>>(x, W0t, Tt, nullptr,
                                                   NN, 512, 1024, 4, 1024);
  // G2: H0 = relu(adj @ T0 + b0)               [16384][512] bf16
  if (useAdjB) {
    gemm256<<<dim3(128, 2), 512, 0, stream>>>(adjb, Tt, Pp, NN, 512, NN, 2, NN / 2);
    reduceK_kernel<2, true><<<dim3(8192), 256, 0, stream>>>(Pp, b0, H, NN * 512, 511);
  } else {
    gemm_bt<1, false><<<dim3(512), 256, 0, stream>>>(adj, Tt, H, b0,
                                                     NN, 512, NN, 4, NN);
  }
  // G3: T1t = (H0 @ W1)^T
  gemm_bt<0, true><<<dim3(512), 256, 0, stream>>>(H, W1t, Tt, nullptr,
                                                  NN, 512, 512, 4, 512);
  // G4: H1 = relu(adj @ T1 + b1)
  if (useAdjB) {
    gemm256<<<dim3(128, 2), 512, 0, stream>>>(adjb, Tt, Pp, NN, 512, NN, 2, NN / 2);
    reduceK_kernel<2, true><<<dim3(8192), 256, 0, stream>>>(Pp, b1, H, NN * 512, 511);
  } else {
    gemm_bt<1, false><<<dim3(512), 256, 0, stream>>>(adj, Tt, H, b1,
                                                     NN, 512, NN, 4, NN);
  }
  // G5: T2t = (H1 @ W2)^T                      [256][16384] bf16
  gemm_bt<0, true><<<dim3(256), 256, 0, stream>>>(H, W2t, Tt, nullptr,
                                                  NN, 256, 512, 2, 512);
  // G6: EMB = adj @ T2 + b2                    split-K=4 fp32 partials
  if (useAdjB) {
    gemm256<<<dim3(64, 4), 512, 0, stream>>>(adjb, Tt, Pp, NN, 256, NN, 1, NN / 4);
    reduceK_kernel<4, false><<<dim3(4096), 256, 0, stream>>>(Pp, b2, EMB, NN * 256, 255);
  } else {
    gemm_bt<3, false><<<dim3(256, 2), 256, 0, stream>>>(adj, Tt, Pp, nullptr,
                                                        NN, 256, NN, 2, NN / 2);
    reduceK_kernel<2, false><<<dim3(4096), 256, 0, stream>>>(Pp, b2, EMB, NN * 256, 255);
  }
  // head: gather + MLP + logits
  head_kernel<<<dim3((P + 63) / 64), 256, 0, stream>>>(EMB, tf, gi, Wh1t, bh1,
                                                       Wh2, bh2, out, P);
}